// Round 4
// baseline (2025.290 us; speedup 1.0000x reference)
//
#include <hip/hip_runtime.h>
#include <cstdint>

// Problem constants: B=32, C=1, H=W=512, 200 iters, top-100
#define IW 512
#define IH 512
#define HW 262144
#define NIMG 32
#define MAXD 100
// Propagation: 128x64 tile (2 cols/lane), halo 8, core 112x48, 25 passes x 8 iters
#define TW 128
#define TH 64
#define HALO 8
#define CX 112
#define CY 48
#define NPASS 25
#define NTX 5              // ceil(512/112)
#define NTY 11             // ceil(512/48)
#define GH 32768           // global hash slots per image
#define HASHN 2048         // LDS hash slots per block

// ---------------- workspace layout (bytes) ----------------
// [0, 32MB)      labA during prop; AFTER prop (labels live in labB):
//                  ghkey 4MB @0, ghval 4MB @4MB, small arrays @8.5MB
// [33554688, ..) labB  (final labels; NPASS=25 odd)
#define OFF_LABB  33554688ull
#define OFF_GHV   4194304ull
#define OFF_SMALL 8388608ull

__device__ __forceinline__ int imax3(int a, int b, int c) {
    int m = a > b ? a : b;
    return m > c ? m : c;
}

// ---------------- 1. init labels: lab = fg ? (pixelIdx+1) : 0 ----------------
__global__ __launch_bounds__(256) void init_labels(const float4* __restrict__ img,
                                                   int4* __restrict__ lab) {
    const size_t n = (size_t)NIMG * HW / 4;
    const size_t stride = (size_t)gridDim.x * 256;
    for (size_t i = (size_t)blockIdx.x * 256 + threadIdx.x; i < n; i += stride) {
        float4 f = img[i];
        int p = (int)((i * 4) & (HW - 1));   // pixel index within image (HW%4==0)
        int4 o;
        o.x = (f.x > 127.5f) ? p + 1 : 0;    // x/255>0.5 <=> x>127.5 (ints 0..255)
        o.y = (f.y > 127.5f) ? p + 2 : 0;
        o.z = (f.z > 127.5f) ? p + 3 : 0;
        o.w = (f.w > 127.5f) ? p + 4 : 0;
        lab[i] = o;
    }
}

// ---------------- 2. propagation: 8 masked maxpool iters per pass ------------
// 1 wave per 128x64 tile; lane L owns columns x0+2L (a[]) and x0+2L+1 (b[]).
// Horizontal 3-max: col 2L needs (b[L-1], a[L], b[L]) -> 1 shfl_up(b);
//                   col 2L+1 needs (a[L], b[L], a[L+1]) -> 1 shfl_down(a).
// => 2 shuffles per 128 pixels per iter (was 2 per 64). Shuffle garbage at
// lanes 0/63 + out-of-tile rows treated as 0 corrupts <=8 px inward in 8
// iters -> absorbed by halo; core = local cols 8..119 (lanes 4..59), rows 8..55.
// mask == (v != 0): fg labels monotone >=1, bg stays 0; OOB = 0 matches the
// reference's reduce_window init=0 padding.
__global__ __launch_bounds__(64) void prop_pass(const int* __restrict__ in,
                                                int* __restrict__ out) {
    const int img = blockIdx.z;
    const int x0 = blockIdx.x * CX - HALO;       // even (CX even, HALO even)
    const int y0 = blockIdx.y * CY - HALO;
    const int lane = threadIdx.x;
    const int xe = x0 + 2 * lane;                // even column of this lane
    const bool colok = (xe >= 0) && (xe < IW);   // pair fully in or fully out
    const int2* __restrict__ ip2 = (const int2*)(in + (size_t)img * HW);
    int2* __restrict__ op2 = (int2*)(out + (size_t)img * HW);

    int a[TH], b[TH];
#pragma unroll
    for (int i = 0; i < TH; ++i) {
        int gy = y0 + i;
        int2 ld = make_int2(0, 0);
        if (colok && gy >= 0 && gy < IH) ld = ip2[gy * (IW / 2) + (xe >> 1)];
        a[i] = ld.x; b[i] = ld.y;
    }

#pragma unroll 1
    for (int it = 0; it < HALO; ++it) {
        int la0 = __shfl_up(b[0], 1, 64);
        int ra0 = __shfl_down(a[0], 1, 64);
        int haP = 0, hbP = 0;
        int haC = imax3(la0, a[0], b[0]);
        int hbC = imax3(a[0], b[0], ra0);
#pragma unroll
        for (int i = 0; i < TH; ++i) {
            int haN = 0, hbN = 0;
            if (i < TH - 1) {
                int l = __shfl_up(b[i + 1], 1, 64);
                int r = __shfl_down(a[i + 1], 1, 64);
                haN = imax3(l, a[i + 1], b[i + 1]);
                hbN = imax3(a[i + 1], b[i + 1], r);
            }
            int na = imax3(haP, haC, haN);
            int nb = imax3(hbP, hbC, hbN);
            a[i] = (a[i] == 0) ? 0 : na;
            b[i] = (b[i] == 0) ? 0 : nb;
            haP = haC; haC = haN; hbP = hbC; hbC = hbN;
        }
    }

    // write 112x48 core (lanes 4..59 = local cols 8..119)
    if (lane >= 4 && lane < 60 && colok) {
#pragma unroll
        for (int i = HALO; i < TH - HALO; ++i) {
            int gy = y0 + i;                      // >= 0 since i >= 8
            if (gy < IH) op2[gy * (IW / 2) + (xe >> 1)] = make_int2(a[i], b[i]);
        }
    }
}

// ---------------- global per-image (label,count) hash ------------------------
__device__ __forceinline__ void ghash_add(unsigned* __restrict__ gk,
                                          unsigned* __restrict__ gv,
                                          unsigned key, unsigned cnt) {
    unsigned h = (key * 2654435761u) >> 17;      // top 15 bits
    for (unsigned probe = 0; probe < GH; ++probe) {
        unsigned idx = (h + probe) & (GH - 1);
        unsigned k = gk[idx];
        if (k == key) { atomicAdd(&gv[idx], cnt); return; }
        if (k == 0u) {
            unsigned old = atomicCAS(&gk[idx], 0u, key);
            if (old == 0u || old == key) { atomicAdd(&gv[idx], cnt); return; }
        }
    }
}

// ---------------- 3. per-label counts: wave run-aggregation + LDS hash -------
// A wave covers 64 consecutive columns of one row -> labels come in runs.
// Ballot-loop over distinct labels: one LDS-hash update of popcll(mask) per
// distinct label per wave (the giant cluster previously caused 64-way
// same-address atomic serialization per pixel).
__global__ __launch_bounds__(256) void count_pass(const int* __restrict__ lab,
                                                  unsigned* __restrict__ gk,
                                                  unsigned* __restrict__ gv) {
    __shared__ unsigned hkey[HASHN];
    __shared__ unsigned hval[HASHN];
    const int img = blockIdx.y;
    const int rb = blockIdx.x * 16;
    for (int t = threadIdx.x; t < HASHN; t += 256) { hkey[t] = 0; hval[t] = 0; }
    __syncthreads();
    const int* lp = lab + (size_t)img * HW + rb * IW;
    unsigned* gki = gk + (size_t)img * GH;
    unsigned* gvi = gv + (size_t)img * GH;
    const int lane = threadIdx.x & 63;
    for (int p = threadIdx.x; p < 16 * IW; p += 256) {   // 8192/256 exact: no tail
        unsigned ul = (unsigned)lp[p];
        unsigned long long act = __ballot(ul != 0u);
        while (act) {
            int src = __ffsll((long long)act) - 1;
            unsigned cur = (unsigned)__shfl((int)ul, src, 64);
            unsigned long long mm = __ballot(ul == cur);
            if (lane == src) {
                unsigned cnt = (unsigned)__popcll(mm);
                unsigned h = (cur * 2654435761u) >> 21;  // 11-bit LDS hash
                bool done = false;
                for (int pr = 0; pr < 32; ++pr) {
                    unsigned idx = (h + pr) & (HASHN - 1);
                    unsigned k = hkey[idx];
                    if (k == cur) { atomicAdd(&hval[idx], cnt); done = true; break; }
                    if (k == 0u) {
                        unsigned old = atomicCAS(&hkey[idx], 0u, cur);
                        if (old == 0u || old == cur) { atomicAdd(&hval[idx], cnt); done = true; break; }
                    }
                }
                if (!done) ghash_add(gki, gvi, cur, cnt);
            }
            act &= ~mm;
        }
    }
    __syncthreads();
    for (int t = threadIdx.x; t < HASHN; t += 256)
        if (hkey[t]) ghash_add(gki, gvi, hkey[t], hval[t]);
}

// ---------------- 4. exact top-100 per image over the hash -------------------
// key = ((count<<19)|(HW-label))<<15 | slot  (count desc, label asc == lax.top_k
// tie order; slot bits make argmax extraction trivial; keys unique).
__global__ __launch_bounds__(1024) void topk(const unsigned* __restrict__ gk,
                                             const unsigned* __restrict__ gv,
                                             unsigned* __restrict__ rank_count,
                                             unsigned* __restrict__ lab_asc,
                                             unsigned* __restrict__ rank_of_lab) {
    const int img = blockIdx.x;
    const int t = threadIdx.x;
    const unsigned* gki = gk + (size_t)img * GH;
    const unsigned* gvi = gv + (size_t)img * GH;
    unsigned long long karg[32];
#pragma unroll
    for (int j = 0; j < 32; ++j) {
        int slot = j * 1024 + t;
        unsigned lb = gki[slot];
        unsigned long long key = 0;
        if (lb) {
            unsigned c = gvi[slot];
            key = ((((unsigned long long)c << 19) | (unsigned)(HW - lb)) << 15)
                  | (unsigned)slot;
        }
        karg[j] = key;
    }
    unsigned live = 0xFFFFFFFFu;
    __shared__ unsigned long long wred[16];
    __shared__ unsigned long long winner;
    __shared__ unsigned s_cnt[MAXD], s_lab[MAXD];
    const int lane = t & 63, wid = t >> 6;
    for (int r = 0; r < MAXD; ++r) {
        unsigned long long m = 0;
#pragma unroll
        for (int j = 0; j < 32; ++j) {
            unsigned long long cand = ((live >> j) & 1u) ? karg[j] : 0ull;
            if (cand > m) m = cand;
        }
        for (int s = 1; s < 64; s <<= 1) {
            unsigned long long o = (unsigned long long)__shfl_xor((long long)m, s, 64);
            if (o > m) m = o;
        }
        if (lane == 0) wred[wid] = m;
        __syncthreads();
        if (wid == 0) {
            unsigned long long w = (lane < 16) ? wred[lane] : 0ull;
            for (int s = 1; s < 16; s <<= 1) {
                unsigned long long o = (unsigned long long)__shfl_xor((long long)w, s, 64);
                if (o > w) w = o;
            }
            if (lane == 0) winner = w;
        }
        __syncthreads();
        unsigned long long w = winner;
        int slot = (int)(w & 32767ull);
        if (t == (slot & 1023)) live &= ~(1u << (slot >> 10));   // clear extracted
        if (t == 0) {
            s_cnt[r] = (unsigned)(w >> 34);
            unsigned lw = (unsigned)((w >> 15) & 0x7FFFFull);
            // empty ranks get unique fake labels > HW (never match real pixels)
            s_lab[r] = (w == 0ull) ? (unsigned)(HW + 1 + r) : (unsigned)(HW - lw);
        }
        __syncthreads();
    }
    if (t < MAXD) {
        rank_count[img * MAXD + t] = s_cnt[t];
        unsigned lb = s_lab[t];
        int lr = 0;
        for (int j = 0; j < MAXD; ++j) lr += (s_lab[j] < lb);   // labels unique
        lab_asc[img * MAXD + lr] = lb;
        rank_of_lab[img * MAXD + lr] = (unsigned)t;
    }
}

// ---------------- 5. bbox: wave run-aggregation + LDS pre-reduction ----------
// Per distinct label per wave: x-range from ffs/clz of the match mask (wave =
// 64 consecutive cols of one row), y uniform -> 4 LDS atomics per run.
__global__ __launch_bounds__(256) void bbox_pass(const int* __restrict__ lab,
                                                 const unsigned* __restrict__ lab_asc,
                                                 const unsigned* __restrict__ rank_of_lab,
                                                 unsigned* __restrict__ bxmin,
                                                 unsigned* __restrict__ bymin,
                                                 unsigned* __restrict__ bxmax,
                                                 unsigned* __restrict__ bymax) {
    __shared__ unsigned sl[MAXD], sr[MAXD];
    __shared__ unsigned sxmin[MAXD], symin[MAXD], sxmax[MAXD], symax[MAXD];
    const int img = blockIdx.y;
    const int rb = blockIdx.x * 16;
    const int t = threadIdx.x, lane = t & 63;
    if (t < MAXD) {
        sl[t] = lab_asc[img * MAXD + t];
        sr[t] = rank_of_lab[img * MAXD + t];
        sxmin[t] = 0xFFFFFFFFu; symin[t] = 0xFFFFFFFFu; sxmax[t] = 0u; symax[t] = 0u;
    }
    __syncthreads();
    const int* lp = lab + (size_t)img * HW + rb * IW;
    for (int p = t; p < 16 * IW; p += 256) {
        unsigned ul = (unsigned)lp[p];
        unsigned y = (unsigned)(rb + (p >> 9));
        unsigned xb = (unsigned)((p - lane) & (IW - 1));   // wave-uniform col base
        unsigned long long act = __ballot(ul != 0u);
        while (act) {
            int src = __ffsll((long long)act) - 1;
            unsigned cur = (unsigned)__shfl((int)ul, src, 64);
            unsigned long long mm = __ballot(ul == cur);
            if (lane == src) {
                int lo = 0, hi = MAXD - 1, f = -1;         // labels unique, sorted
                while (lo <= hi) {
                    int mid = (lo + hi) >> 1;
                    unsigned sv = sl[mid];
                    if (sv == cur) { f = mid; break; }
                    if (sv < cur) lo = mid + 1; else hi = mid - 1;
                }
                if (f >= 0) {
                    unsigned rk = sr[f];
                    unsigned x0 = xb + (unsigned)(__ffsll((long long)mm) - 1);
                    unsigned x1 = xb + (unsigned)(63 - __clzll(mm));
                    atomicMin(&sxmin[rk], x0); atomicMax(&sxmax[rk], x1);
                    atomicMin(&symin[rk], y);  atomicMax(&symax[rk], y);
                }
            }
            act &= ~mm;
        }
    }
    __syncthreads();
    if (t < MAXD && sxmin[t] != 0xFFFFFFFFu) {
        atomicMin(&bxmin[img * MAXD + t], sxmin[t]);
        atomicMax(&bxmax[img * MAXD + t], sxmax[t]);
        atomicMin(&bymin[img * MAXD + t], symin[t]);
        atomicMax(&bymax[img * MAXD + t], symax[t]);
    }
}

// ---------------- 6. finalize: [xmin,ymin,xmax,ymax] or zeros ----------------
__global__ __launch_bounds__(256) void final_out(const unsigned* __restrict__ rank_count,
                                                 const unsigned* __restrict__ bxmin,
                                                 const unsigned* __restrict__ bymin,
                                                 const unsigned* __restrict__ bxmax,
                                                 const unsigned* __restrict__ bymax,
                                                 float* __restrict__ out) {
    int id = blockIdx.x * 256 + threadIdx.x;
    if (id >= NIMG * MAXD) return;
    unsigned c = rank_count[id];
    float4 b = make_float4(0.f, 0.f, 0.f, 0.f);
    if (c) b = make_float4((float)bxmin[id], (float)bymin[id],
                           (float)bxmax[id], (float)bymax[id]);
    reinterpret_cast<float4*>(out)[id] = b;
}

// ---------------- launch ----------------
extern "C" void kernel_launch(void* const* d_in, const int* in_sizes, int n_in,
                              void* d_out, int out_size, void* d_ws, size_t ws_size,
                              hipStream_t stream) {
    (void)in_sizes; (void)n_in; (void)out_size; (void)ws_size;
    const float* img = (const float*)d_in[0];
    char* ws = (char*)d_ws;

    int* labA = (int*)ws;
    int* labB = (int*)(ws + OFF_LABB);
    unsigned* ghk = (unsigned*)ws;                       // alias labA (dead after prop)
    unsigned* ghv = (unsigned*)(ws + OFF_GHV);
    char* sm = ws + OFF_SMALL;
    unsigned* rank_count  = (unsigned*)sm;
    unsigned* lab_asc     = rank_count + NIMG * MAXD;
    unsigned* rank_of_lab = lab_asc + NIMG * MAXD;
    unsigned* bxmin = rank_of_lab + NIMG * MAXD;
    unsigned* bymin = bxmin + NIMG * MAXD;
    unsigned* bxmax = bymin + NIMG * MAXD;
    unsigned* bymax = bxmax + NIMG * MAXD;
    float* out = (float*)d_out;

    init_labels<<<2048, 256, 0, stream>>>((const float4*)img, (int4*)labA);

    // 25 passes x 8 iterations = exactly 200 masked maxpool iterations
    dim3 pg(NTX, NTY, NIMG);
    const int* pin = labA; int* pout = labB;
    for (int p = 0; p < NPASS; ++p) {
        prop_pass<<<pg, 64, 0, stream>>>(pin, pout);
        int* tmp = (int*)pin; pin = pout; pout = tmp;
    }
    // NPASS odd -> final labels in labB; labA region now free for hash+small

    hipMemsetAsync(ghk, 0, 2ull * 4194304ull, stream);   // ghkey+ghval contiguous 8MB
    hipMemsetAsync(bxmin, 0xFF, NIMG * MAXD * 4, stream);
    hipMemsetAsync(bymin, 0xFF, NIMG * MAXD * 4, stream);
    hipMemsetAsync(bxmax, 0, NIMG * MAXD * 4, stream);
    hipMemsetAsync(bymax, 0, NIMG * MAXD * 4, stream);

    count_pass<<<dim3(32, NIMG), 256, 0, stream>>>(pin, ghk, ghv);
    topk<<<NIMG, 1024, 0, stream>>>(ghk, ghv, rank_count, lab_asc, rank_of_lab);
    bbox_pass<<<dim3(32, NIMG), 256, 0, stream>>>(pin, lab_asc, rank_of_lab,
                                                  bxmin, bymin, bxmax, bymax);
    final_out<<<(NIMG * MAXD + 255) / 256, 256, 0, stream>>>(rank_count, bxmin, bymin,
                                                             bxmax, bymax, out);
}

// Round 5
// 1267.865 us; speedup vs baseline: 1.5974x; 1.5974x over previous
//
#include <hip/hip_runtime.h>
#include <cstdint>

// Problem constants: B=32, C=1, H=W=512, 200 iters, top-100
#define IW 512
#define IH 512
#define HW 262144
#define NIMG 32
#define MAXD 100
// Propagation: 128x64 tile (2 cols/lane), halo 8, core 112x48, 25 passes x 8 iters
#define TH 64
#define HALO 8
#define CX 112
#define CY 48
#define NPASS 25
#define NTX 5              // ceil(512/112)
#define NTY 11             // ceil(512/48)
#define GH 32768           // global hash slots per image (distinct labels ~few K)
#define SLOTS 2048         // LDS hash slots per block

// ---------------- workspace layout (bytes) ----------------
// [0, 32MB)  labA during prop. AFTER prop (labels live in labB):
//   gk   @ 0      4MB   label keys        (memset 0)
//   gcnt @ 4MB    4MB   counts            (memset 0)
//   gx1  @ 8MB    4MB   xmax              (memset 0)
//   gy1  @ 12MB   4MB   ymax              (memset 0)
//   gx0  @ 16MB   4MB   xmin              (memset 0xFF)
//   gy0  @ 20MB   4MB   ymin              (memset 0xFF)
//   small@ 24MB         rank_count, rank_slot
// [33554688, ..) labB (final labels; NPASS=25 odd)
#define OFF_LABB  33554688ull
#define OFF_SMALL 25165824ull

__device__ __forceinline__ int imax3(int a, int b, int c) {
    int m = a > b ? a : b;
    return m > c ? m : c;
}

// ---------------- 1. init labels: lab = fg ? (pixelIdx+1) : 0 ----------------
__global__ __launch_bounds__(256) void init_labels(const float4* __restrict__ img,
                                                   int4* __restrict__ lab) {
    const size_t n = (size_t)NIMG * HW / 4;
    const size_t stride = (size_t)gridDim.x * 256;
    for (size_t i = (size_t)blockIdx.x * 256 + threadIdx.x; i < n; i += stride) {
        float4 f = img[i];
        int p = (int)((i * 4) & (HW - 1));   // pixel index within image (HW%4==0)
        int4 o;
        o.x = (f.x > 127.5f) ? p + 1 : 0;    // x/255>0.5 <=> x>127.5 (ints 0..255)
        o.y = (f.y > 127.5f) ? p + 2 : 0;
        o.z = (f.z > 127.5f) ? p + 3 : 0;
        o.w = (f.w > 127.5f) ? p + 4 : 0;
        lab[i] = o;
    }
}

// ---------------- 2. propagation: 8 masked maxpool iters per pass ------------
// 1 wave per 128x64 tile; lane L owns columns x0+2L (a[]) and x0+2L+1 (b[]).
// Horizontal 3-max: col 2L needs (b[L-1], a[L], b[L]) -> 1 shfl_up(b);
//                   col 2L+1 needs (a[L], b[L], a[L+1]) -> 1 shfl_down(a).
// Edge garbage corrupts <=8 px inward in 8 iters -> absorbed by halo;
// core = local cols 8..119 (lanes 4..59), rows 8..55.
// mask == (v != 0): fg labels monotone >=1, bg stays 0; OOB = 0 matches the
// reference's reduce_window init=0 padding.
__global__ __launch_bounds__(64) void prop_pass(const int* __restrict__ in,
                                                int* __restrict__ out) {
    const int img = blockIdx.z;
    const int x0 = blockIdx.x * CX - HALO;       // even (CX even, HALO even)
    const int y0 = blockIdx.y * CY - HALO;
    const int lane = threadIdx.x;
    const int xe = x0 + 2 * lane;                // even column of this lane
    const bool colok = (xe >= 0) && (xe < IW);   // pair fully in or fully out
    const int2* __restrict__ ip2 = (const int2*)(in + (size_t)img * HW);
    int2* __restrict__ op2 = (int2*)(out + (size_t)img * HW);

    int a[TH], b[TH];
#pragma unroll
    for (int i = 0; i < TH; ++i) {
        int gy = y0 + i;
        int2 ld = make_int2(0, 0);
        if (colok && gy >= 0 && gy < IH) ld = ip2[gy * (IW / 2) + (xe >> 1)];
        a[i] = ld.x; b[i] = ld.y;
    }

#pragma unroll 1
    for (int it = 0; it < HALO; ++it) {
        int la0 = __shfl_up(b[0], 1, 64);
        int ra0 = __shfl_down(a[0], 1, 64);
        int haP = 0, hbP = 0;
        int haC = imax3(la0, a[0], b[0]);
        int hbC = imax3(a[0], b[0], ra0);
#pragma unroll
        for (int i = 0; i < TH; ++i) {
            int haN = 0, hbN = 0;
            if (i < TH - 1) {
                int l = __shfl_up(b[i + 1], 1, 64);
                int r = __shfl_down(a[i + 1], 1, 64);
                haN = imax3(l, a[i + 1], b[i + 1]);
                hbN = imax3(a[i + 1], b[i + 1], r);
            }
            int na = imax3(haP, haC, haN);
            int nb = imax3(hbP, hbC, hbN);
            a[i] = (a[i] == 0) ? 0 : na;
            b[i] = (b[i] == 0) ? 0 : nb;
            haP = haC; haC = haN; hbP = hbC; hbC = hbN;
        }
    }

    // write 112x48 core (lanes 4..59 = local cols 8..119)
    if (lane >= 4 && lane < 60 && colok) {
#pragma unroll
        for (int i = HALO; i < TH - HALO; ++i) {
            int gy = y0 + i;                      // >= 0 since i >= 8
            if (gy < IH) op2[gy * (IW / 2) + (xe >> 1)] = make_int2(a[i], b[i]);
        }
    }
}

// -------- global per-image hash: find-or-insert, returns slot index ----------
__device__ __forceinline__ unsigned gfind(unsigned* __restrict__ gk, unsigned key) {
    unsigned h = (key * 2654435761u) >> 17;      // top 15 bits
    for (unsigned pr = 0; pr < GH; ++pr) {
        unsigned idx = (h + pr) & (GH - 1);
        unsigned k = gk[idx];
        if (k == key) return idx;
        if (k == 0u) {
            unsigned old = atomicCAS(&gk[idx], 0u, key);
            if (old == 0u || old == key) return idx;
        }
    }
    return h;   // unreachable unless hash full (distinct labels < GH)
}

// ---------------- 3. fused per-label stats: count + bbox in ONE scan ---------
// Per-pixel PARALLEL (all 64 lanes probe/update independently -- the round-2
// ballot-loop serialized a 7-deep LDS latency chain through one lane per
// distinct label and measured 646us; per-pixel was <87us in round 1).
// LDS hash per block (16 rows), merged into global per-image hash.
__global__ __launch_bounds__(256) void stat_pass(const int* __restrict__ lab,
                                                 unsigned* __restrict__ gk,
                                                 unsigned* __restrict__ gcnt,
                                                 unsigned* __restrict__ gx0,
                                                 unsigned* __restrict__ gx1,
                                                 unsigned* __restrict__ gy0,
                                                 unsigned* __restrict__ gy1) {
    __shared__ unsigned hk[SLOTS], hc[SLOTS];
    __shared__ unsigned sx0[SLOTS], sx1[SLOTS], sy0[SLOTS], sy1[SLOTS];
    const int img = blockIdx.y;
    const int rb = blockIdx.x * 16;
    const int t = threadIdx.x;
    for (int i = t; i < SLOTS; i += 256) {
        hk[i] = 0; hc[i] = 0;
        sx0[i] = 0xFFFFFFFFu; sy0[i] = 0xFFFFFFFFu; sx1[i] = 0; sy1[i] = 0;
    }
    __syncthreads();
    unsigned* gki = gk + (size_t)img * GH;
    unsigned* gci = gcnt + (size_t)img * GH;
    unsigned* gx0i = gx0 + (size_t)img * GH;
    unsigned* gx1i = gx1 + (size_t)img * GH;
    unsigned* gy0i = gy0 + (size_t)img * GH;
    unsigned* gy1i = gy1 + (size_t)img * GH;

    const int4* lp = (const int4*)(lab + (size_t)img * HW + rb * IW);
    for (int i = t; i < 16 * IW / 4; i += 256) {     // 2048 int4, no tail
        int4 v = lp[i];
        unsigned y = (unsigned)(rb + (i >> 7));       // 128 int4 per row
        unsigned xb = (unsigned)((i & 127) << 2);
        int larr[4] = {v.x, v.y, v.z, v.w};
#pragma unroll
        for (int e = 0; e < 4; ++e) {
            unsigned l = (unsigned)larr[e];
            if (!l) continue;
            unsigned x = xb + (unsigned)e;
            unsigned h = (l * 2654435761u) >> 21;     // 11-bit LDS hash
            int idx = -1;
            for (int pr = 0; pr < 32; ++pr) {
                unsigned j = (h + pr) & (SLOTS - 1);
                unsigned k = hk[j];
                if (k == l) { idx = (int)j; break; }
                if (k == 0u) {
                    unsigned old = atomicCAS(&hk[j], 0u, l);
                    if (old == 0u || old == l) { idx = (int)j; break; }
                }
            }
            if (idx >= 0) {
                atomicAdd(&hc[idx], 1u);
                atomicMin(&sx0[idx], x); atomicMax(&sx1[idx], x);
                atomicMin(&sy0[idx], y); atomicMax(&sy1[idx], y);
            } else {                                  // rare LDS overflow
                unsigned g = gfind(gki, l);
                atomicAdd(&gci[g], 1u);
                atomicMin(&gx0i[g], x); atomicMax(&gx1i[g], x);
                atomicMin(&gy0i[g], y); atomicMax(&gy1i[g], y);
            }
        }
    }
    __syncthreads();
    for (int i = t; i < SLOTS; i += 256) {
        unsigned k = hk[i];
        if (!k) continue;
        unsigned g = gfind(gki, k);
        atomicAdd(&gci[g], hc[i]);
        atomicMin(&gx0i[g], sx0[i]); atomicMax(&gx1i[g], sx1[i]);
        atomicMin(&gy0i[g], sy0[i]); atomicMax(&gy1i[g], sy1[i]);
    }
}

// ---------------- 4. exact top-100 per image over the hash -------------------
// key = ((count<<19)|(HW-label))<<15 | slot  (count desc, label asc == lax.top_k
// tie order; slot bits let final_out gather the bbox; keys unique).
__global__ __launch_bounds__(1024) void topk(const unsigned* __restrict__ gk,
                                             const unsigned* __restrict__ gcnt,
                                             unsigned* __restrict__ rank_count,
                                             unsigned* __restrict__ rank_slot) {
    const int img = blockIdx.x;
    const int t = threadIdx.x;
    const unsigned* gki = gk + (size_t)img * GH;
    const unsigned* gci = gcnt + (size_t)img * GH;
    unsigned long long karg[32];
#pragma unroll
    for (int j = 0; j < 32; ++j) {
        int slot = j * 1024 + t;
        unsigned lb = gki[slot];
        unsigned long long key = 0;
        if (lb) {
            unsigned c = gci[slot];
            key = ((((unsigned long long)c << 19) | (unsigned)(HW - lb)) << 15)
                  | (unsigned)slot;
        }
        karg[j] = key;
    }
    unsigned live = 0xFFFFFFFFu;
    __shared__ unsigned long long wred[16];
    __shared__ unsigned long long winner;
    __shared__ unsigned s_cnt[MAXD], s_slot[MAXD];
    const int lane = t & 63, wid = t >> 6;
    for (int r = 0; r < MAXD; ++r) {
        unsigned long long m = 0;
#pragma unroll
        for (int j = 0; j < 32; ++j) {
            unsigned long long cand = ((live >> j) & 1u) ? karg[j] : 0ull;
            if (cand > m) m = cand;
        }
        for (int s = 1; s < 64; s <<= 1) {
            unsigned long long o = (unsigned long long)__shfl_xor((long long)m, s, 64);
            if (o > m) m = o;
        }
        if (lane == 0) wred[wid] = m;
        __syncthreads();
        if (wid == 0) {
            unsigned long long w = (lane < 16) ? wred[lane] : 0ull;
            for (int s = 1; s < 16; s <<= 1) {
                unsigned long long o = (unsigned long long)__shfl_xor((long long)w, s, 64);
                if (o > w) w = o;
            }
            if (lane == 0) winner = w;
        }
        __syncthreads();
        unsigned long long w = winner;
        int slot = (int)(w & 32767ull);
        // safe when w==0: then no live nonzero keys remain, clearing is harmless
        if (t == (slot & 1023)) live &= ~(1u << (slot >> 10));
        if (t == 0) { s_cnt[r] = (unsigned)(w >> 34); s_slot[r] = (unsigned)(w & 32767ull); }
        __syncthreads();
    }
    if (t < MAXD) {
        rank_count[img * MAXD + t] = s_cnt[t];
        rank_slot[img * MAXD + t] = s_slot[t];
    }
}

// ---------------- 5. finalize: gather [xmin,ymin,xmax,ymax] or zeros ---------
__global__ __launch_bounds__(256) void final_out(const unsigned* __restrict__ rank_count,
                                                 const unsigned* __restrict__ rank_slot,
                                                 const unsigned* __restrict__ gx0,
                                                 const unsigned* __restrict__ gx1,
                                                 const unsigned* __restrict__ gy0,
                                                 const unsigned* __restrict__ gy1,
                                                 float* __restrict__ out) {
    int id = blockIdx.x * 256 + threadIdx.x;
    if (id >= NIMG * MAXD) return;
    unsigned c = rank_count[id];
    float4 b = make_float4(0.f, 0.f, 0.f, 0.f);
    if (c) {
        int img = id / MAXD;
        size_t g = (size_t)img * GH + rank_slot[id];
        b = make_float4((float)gx0[g], (float)gy0[g], (float)gx1[g], (float)gy1[g]);
    }
    reinterpret_cast<float4*>(out)[id] = b;
}

// ---------------- launch ----------------
extern "C" void kernel_launch(void* const* d_in, const int* in_sizes, int n_in,
                              void* d_out, int out_size, void* d_ws, size_t ws_size,
                              hipStream_t stream) {
    (void)in_sizes; (void)n_in; (void)out_size; (void)ws_size;
    const float* img = (const float*)d_in[0];
    char* ws = (char*)d_ws;

    int* labA = (int*)ws;
    int* labB = (int*)(ws + OFF_LABB);
    // hash region aliases labA (dead after the last prop pass reads it)
    unsigned* gk   = (unsigned*)ws;                       // 0..4MB   (zeros)
    unsigned* gcnt = (unsigned*)(ws + 4194304ull);        // 4..8MB   (zeros)
    unsigned* gx1  = (unsigned*)(ws + 8388608ull);        // 8..12MB  (zeros)
    unsigned* gy1  = (unsigned*)(ws + 12582912ull);       // 12..16MB (zeros)
    unsigned* gx0  = (unsigned*)(ws + 16777216ull);       // 16..20MB (0xFF)
    unsigned* gy0  = (unsigned*)(ws + 20971520ull);       // 20..24MB (0xFF)
    unsigned* rank_count = (unsigned*)(ws + OFF_SMALL);
    unsigned* rank_slot  = (unsigned*)(ws + OFF_SMALL + 16384ull);
    float* out = (float*)d_out;

    init_labels<<<2048, 256, 0, stream>>>((const float4*)img, (int4*)labA);

    // 25 passes x 8 iterations = exactly 200 masked maxpool iterations
    dim3 pg(NTX, NTY, NIMG);
    const int* pin = labA; int* pout = labB;
    for (int p = 0; p < NPASS; ++p) {
        prop_pass<<<pg, 64, 0, stream>>>(pin, pout);
        int* tmp = (int*)pin; pin = pout; pout = tmp;
    }
    // NPASS odd -> final labels in labB; labA region now free for the hash

    hipMemsetAsync(gk, 0, 16777216ull, stream);           // gk,gcnt,gx1,gy1
    hipMemsetAsync(gx0, 0xFF, 8388608ull, stream);        // gx0,gy0

    stat_pass<<<dim3(32, NIMG), 256, 0, stream>>>(pin, gk, gcnt, gx0, gx1, gy0, gy1);
    topk<<<NIMG, 1024, 0, stream>>>(gk, gcnt, rank_count, rank_slot);
    final_out<<<(NIMG * MAXD + 255) / 256, 256, 0, stream>>>(rank_count, rank_slot,
                                                             gx0, gx1, gy0, gy1, out);
}